// Round 1
// baseline (328.484 us; speedup 1.0000x reference)
//
#include <hip/hip_runtime.h>
#include <math.h>

// Problem constants (fixed shapes from reference)
#define BB 4096
#define LL 50
#define NN 50
#define DD 128

// One block per batch. Restructured computation:
//   alpha depends only on the node index, so histogram indices (cnt[n]) and
//   compute per-node projections -> no gather in the heavy matmul.
__global__ __launch_bounds__(256, 4) void sess_attn(
    const int*   __restrict__ seq_idx,   // [B,L]
    const int*   __restrict__ mask,      // [B,L]
    const float* __restrict__ nodes,     // [B,N,D]
    const float* __restrict__ W_last,    // [D,D]
    const float* __restrict__ W_seq,     // [D,D]
    const float* __restrict__ b_seq,     // [D]
    const float* __restrict__ W_alpha,   // [D]
    float*       __restrict__ out)       // [B*D] v_n, then [B*D] session_graph
{
    const int b   = blockIdx.x;
    const int tid = threadIdx.x;
    const int d   = tid & (DD - 1);   // column 0..127
    const int h   = tid >> 7;         // node-half 0/1

    __shared__ __align__(16) float s_node[NN][DD];   // 25.6 KB
    __shared__ float s_vn[DD];
    __shared__ float s_vnproj[DD];
    __shared__ float s_alpha[NN];
    __shared__ float s_cntf[NN];
    __shared__ int   s_last;

    if (tid < NN) { s_alpha[tid] = 0.f; s_cntf[tid] = 0.f; }

    // Stage nodes[b] (50x128 fp32) into LDS, coalesced float4.
    const float* nb = nodes + (size_t)b * (NN * DD);
    for (int i = tid; i < NN * DD / 4; i += 256)
        ((float4*)s_node)[i] = ((const float4*)nb)[i];

    // seq_len via wave-0 reduction over mask row; last index.
    if (tid < 64) {
        int m = (tid < LL) ? mask[b * LL + tid] : 0;
        for (int off = 32; off; off >>= 1) m += __shfl_down(m, off);
        if (tid == 0) {
            int j = m - 1;
            if (j < 0) j += LL;          // emulate JAX negative-index wrap
            s_last = seq_idx[b * LL + j];
        }
    }
    __syncthreads();   // s_node, s_last, s_alpha/s_cntf init all visible

    // Histogram of masked indices (float mask weight, generic).
    if (tid < LL) {
        float mf = (float)mask[b * LL + tid];
        if (mf != 0.f) atomicAdd(&s_cntf[seq_idx[b * LL + tid]], mf);
    }

    // v_n output + keep in LDS.
    const int last = s_last;
    if (tid < DD) {
        float v = s_node[last][tid];
        s_vn[tid] = v;
        out[(size_t)b * DD + tid] = v;
    }
    __syncthreads();

    // vn_proj[d] = sum_k v_n[k] * W_last[k][d]
    if (tid < DD) {
        float acc = 0.f;
        #pragma unroll 8
        for (int k = 0; k < DD; ++k)
            acc = fmaf(s_vn[k], W_last[k * DD + tid], acc);
        s_vnproj[tid] = acc;
    }
    __syncthreads();

    // Heavy part: node_proj for 25 nodes per half, register-blocked over n.
    const int n0 = h * 25;
    float acc[25];
    #pragma unroll
    for (int j = 0; j < 25; ++j) acc[j] = 0.f;

    for (int k = 0; k < DD; k += 4) {
        float w0 = W_seq[(k + 0) * DD + d];
        float w1 = W_seq[(k + 1) * DD + d];
        float w2 = W_seq[(k + 2) * DD + d];
        float w3 = W_seq[(k + 3) * DD + d];
        #pragma unroll
        for (int j = 0; j < 25; ++j) {
            float4 a = *(const float4*)&s_node[n0 + j][k];   // wave-uniform broadcast
            acc[j] = fmaf(a.x, w0, fmaf(a.y, w1, fmaf(a.z, w2, fmaf(a.w, w3, acc[j]))));
        }
    }

    // alpha_node[n] = sum_d sigmoid(vnproj[d] + node_proj[n][d] + b_seq[d]) * W_alpha[d]
    const float bias = b_seq[d];
    const float wa   = W_alpha[d];
    const float vnp  = s_vnproj[d];
    #pragma unroll
    for (int j = 0; j < 25; ++j) {
        float x = vnp + bias + acc[j];
        float sig = 1.f / (1.f + expf(-x));
        float part = sig * wa;
        for (int off = 32; off; off >>= 1) part += __shfl_down(part, off);
        if ((tid & 63) == 0) atomicAdd(&s_alpha[n0 + j], part);
    }
    __syncthreads();

    // session_graph[d] = sum_n cnt[n]*alpha[n]*nodes[b][n][d]
    if (tid < DD) {
        float acc2 = 0.f;
        #pragma unroll 10
        for (int n = 0; n < NN; ++n)
            acc2 = fmaf(s_cntf[n] * s_alpha[n], s_node[n][tid], acc2);
        out[(size_t)BB * DD + (size_t)b * DD + tid] = acc2;
    }
}

extern "C" void kernel_launch(void* const* d_in, const int* in_sizes, int n_in,
                              void* d_out, int out_size, void* d_ws, size_t ws_size,
                              hipStream_t stream) {
    const int*   seq     = (const int*)  d_in[0];
    const int*   mask    = (const int*)  d_in[1];
    const float* nodes   = (const float*)d_in[2];
    // d_in[3] = batch_size (scalar), unused: shapes are compile-time fixed
    const float* W_last  = (const float*)d_in[4];
    const float* W_seq   = (const float*)d_in[5];
    const float* b_seq   = (const float*)d_in[6];
    const float* W_alpha = (const float*)d_in[7];
    float*       out     = (float*)      d_out;

    sess_attn<<<BB, 256, 0, stream>>>(seq, mask, nodes, W_last, W_seq,
                                      b_seq, W_alpha, out);
}

// Round 2
// 241.642 us; speedup vs baseline: 1.3594x; 1.3594x over previous
//
#include <hip/hip_runtime.h>
#include <math.h>

#define BB 4096
#define LL 50
#define NN 50
#define DD 128

typedef short bf16x8 __attribute__((ext_vector_type(8)));   // 8 bf16 = 4 VGPRs
typedef float f32x4  __attribute__((ext_vector_type(4)));

static __device__ inline unsigned short f32_to_bf16_rne(float f) {
    unsigned int u = __float_as_uint(f);
    u += 0x7FFFu + ((u >> 16) & 1u);   // round-nearest-even
    return (unsigned short)(u >> 16);
}

// Pre-swizzle W_seq (fp32 [k][n], 128x128) into bf16 B-fragment order for
// mfma_f32_16x16x32_bf16:  ws[nt][kk][lane][j] = W_seq[kk*32+(lane>>4)*8+j][nt*16+(lane&15)]
// Total 8*4*64*8 = 16384 bf16 = 32 KB in d_ws.
__global__ void prep_wseq(const float* __restrict__ W_seq,
                          unsigned short* __restrict__ ws)
{
    int t = blockIdx.x * blockDim.x + threadIdx.x;   // 0..2047
    if (t >= 2048) return;
    int lane = t & 63;
    int kk   = (t >> 6) & 3;
    int nt   = t >> 8;
    int n     = nt * 16 + (lane & 15);
    int kbase = kk * 32 + (lane >> 4) * 8;
    unsigned short* dst = ws + (size_t)t * 8;
    #pragma unroll
    for (int j = 0; j < 8; ++j)
        dst[j] = f32_to_bf16_rne(W_seq[(kbase + j) * DD + n]);
}

// One block per batch; 4 waves. Wave w owns m-tile w (node rows 16w..16w+15).
__global__ __launch_bounds__(256, 3) void sess_attn(
    const int*   __restrict__ seq_idx,   // [B,L]
    const int*   __restrict__ mask,      // [B,L]
    const float* __restrict__ nodes,     // [B,N,D]
    const float* __restrict__ W_last,    // [D,D]
    const float* __restrict__ b_seq,     // [D]
    const float* __restrict__ W_alpha,   // [D]
    const unsigned short* __restrict__ wseq_frag,  // d_ws, B-frag order
    float*       __restrict__ out)       // [B*D] v_n, then [B*D] session_graph
{
    const int b    = blockIdx.x;
    const int tid  = threadIdx.x;
    const int lane = tid & 63;
    const int wave = tid >> 6;
    const int col  = lane & 15;
    const int quad = lane >> 4;

    __shared__ __align__(16) float          s_node[NN][DD];   // 25600 B (fp32, exact)
    __shared__ __align__(16) unsigned short s_nbf[64][136];   // 17408 B (bf16 A-tile, padded)
    __shared__ float s_vb[DD];      // vn_proj + b_seq
    __shared__ float s_wa[DD];      // W_alpha
    __shared__ float s_alpha[64];
    __shared__ float s_cntf[NN];
    __shared__ int   s_last;

    if (tid < NN) s_cntf[tid] = 0.f;
    if (tid < DD) s_wa[tid] = W_alpha[tid];

    // Stage nodes[b] (50x128 fp32) into LDS, coalesced float4.
    const float* nb = nodes + (size_t)b * (NN * DD);
    for (int i = tid; i < NN * DD / 4; i += 256)
        ((float4*)s_node)[i] = ((const float4*)nb)[i];

    // seq_len (sum of mask row) and last index — wave 0.
    if (tid < 64) {
        int m = (tid < LL) ? mask[b * LL + tid] : 0;
        for (int off = 32; off; off >>= 1) m += __shfl_down(m, off);
        if (tid == 0) {
            int j = m - 1;
            if (j < 0) j += LL;            // JAX negative-index wrap
            s_last = seq_idx[b * LL + j];
        }
    }
    __syncthreads();   // s_node, s_last, s_wa, s_cntf init visible

    // Histogram of masked indices.
    if (tid < LL) {
        int m = mask[b * LL + tid];
        if (m) atomicAdd(&s_cntf[seq_idx[b * LL + tid]], (float)m);
    }

    const int last = s_last;

    // v_n output (exact fp32 gather).
    if (tid < DD) out[(size_t)b * DD + tid] = s_node[last][tid];

    // vn_proj[d] = sum_k v_n[k]*W_last[k][d]; fold +b_seq here.
    if (tid < DD) {
        float acc = 0.f;
        #pragma unroll 8
        for (int k = 0; k < DD; ++k)
            acc = fmaf(s_node[last][k], W_last[k * DD + tid], acc);
        s_vb[tid] = acc + b_seq[tid];
    }

    // Convert nodes to bf16 A-tile (rows 50..63 zero-padded).
    for (int i = tid; i < 64 * DD; i += 256) {
        int row = i >> 7, c = i & (DD - 1);
        float v = (row < NN) ? s_node[row][c] : 0.f;
        s_nbf[row][c] = f32_to_bf16_rne(v);
    }
    __syncthreads();   // s_nbf, s_vb ready

    // MFMA: m-tile = wave. acc init = vn_proj + b_seq broadcast per column.
    f32x4 acc[8];
    #pragma unroll
    for (int nt = 0; nt < 8; ++nt) {
        float v = s_vb[nt * 16 + col];
        acc[nt] = (f32x4){v, v, v, v};
    }

    const bf16x8* wsf = (const bf16x8*)wseq_frag;
    #pragma unroll
    for (int kk = 0; kk < 4; ++kk) {
        bf16x8 a = *(const bf16x8*)&s_nbf[wave * 16 + col][kk * 32 + quad * 8];
        #pragma unroll
        for (int nt = 0; nt < 8; ++nt) {
            bf16x8 bf = wsf[(nt * 4 + kk) * 64 + lane];
            acc[nt] = __builtin_amdgcn_mfma_f32_16x16x32_bf16(a, bf, acc[nt], 0, 0, 0);
        }
    }

    // Epilogue: alpha[row] = sum_d sigmoid(acc)*W_alpha[d].
    // C layout: col = lane&15, row = quad*4 + r.
    float p[4] = {0.f, 0.f, 0.f, 0.f};
    #pragma unroll
    for (int nt = 0; nt < 8; ++nt) {
        float wa = s_wa[nt * 16 + col];
        #pragma unroll
        for (int r = 0; r < 4; ++r) {
            float sig = 1.f / (1.f + __expf(-acc[nt][r]));
            p[r] = fmaf(sig, wa, p[r]);
        }
    }
    #pragma unroll
    for (int r = 0; r < 4; ++r) {
        float v = p[r];
        v += __shfl_xor(v, 1);
        v += __shfl_xor(v, 2);
        v += __shfl_xor(v, 4);
        v += __shfl_xor(v, 8);
        if (col == 0) s_alpha[wave * 16 + quad * 4 + r] = v;
    }
    __syncthreads();   // s_alpha, s_cntf ready

    // session_graph[d] = sum_n cnt[n]*alpha[n]*nodes[b][n][d]  (fp32 exact-ish)
    if (tid < DD) {
        float acc2 = 0.f;
        #pragma unroll 10
        for (int n = 0; n < NN; ++n)
            acc2 = fmaf(s_cntf[n] * s_alpha[n], s_node[n][tid], acc2);
        out[(size_t)BB * DD + (size_t)b * DD + tid] = acc2;
    }
}

extern "C" void kernel_launch(void* const* d_in, const int* in_sizes, int n_in,
                              void* d_out, int out_size, void* d_ws, size_t ws_size,
                              hipStream_t stream) {
    const int*   seq     = (const int*)  d_in[0];
    const int*   mask    = (const int*)  d_in[1];
    const float* nodes   = (const float*)d_in[2];
    // d_in[3] = batch_size scalar (shapes compile-time fixed)
    const float* W_last  = (const float*)d_in[4];
    const float* W_seq   = (const float*)d_in[5];
    const float* b_seq   = (const float*)d_in[6];
    const float* W_alpha = (const float*)d_in[7];
    float*       out     = (float*)      d_out;

    unsigned short* wsf = (unsigned short*)d_ws;   // 32 KB B-fragments

    prep_wseq<<<8, 256, 0, stream>>>(W_seq, wsf);
    sess_attn<<<BB, 256, 0, stream>>>(seq, mask, nodes, W_last,
                                      b_seq, W_alpha, wsf, out);
}

// Round 3
// 195.796 us; speedup vs baseline: 1.6777x; 1.2342x over previous
//
#include <hip/hip_runtime.h>
#include <math.h>

#define BB 4096
#define LL 50
#define NN 50
#define DD 128

typedef short bf16x8 __attribute__((ext_vector_type(8)));   // 8 bf16 = 4 VGPRs
typedef float f32x4  __attribute__((ext_vector_type(4)));

static __device__ inline unsigned short f32_to_bf16_rne(float f) {
    unsigned int u = __float_as_uint(f);
    u += 0x7FFFu + ((u >> 16) & 1u);   // round-nearest-even
    return (unsigned short)(u >> 16);
}
static __device__ inline float bf16_to_f32(unsigned short h) {
    return __uint_as_float(((unsigned int)h) << 16);
}

// Combined B fragments for mfma_f32_16x16x32_bf16 over extended K=256:
//   kk 0..3 -> W_seq rows kk*32+..,  kk 4..7 -> W_last rows (kk-4)*32+..
// ws[((kk*8+nt)*64+lane)*8 + j] = W[(kk&3)*32 + (lane>>4)*8 + j][nt*16 + (lane&15)]
// Total 8*8*64*8 bf16 = 64 KB in d_ws.
__global__ void prep_w(const float* __restrict__ W_seq,
                       const float* __restrict__ W_last,
                       unsigned short* __restrict__ ws)
{
    int t = blockIdx.x * blockDim.x + threadIdx.x;   // 0..4095
    int lane = t & 63;
    int nt   = (t >> 6) & 7;
    int kk   = t >> 9;
    const float* W = (kk < 4) ? W_seq : W_last;
    int kb = (kk & 3) * 32 + (lane >> 4) * 8;
    int n  = nt * 16 + (lane & 15);
    unsigned short* dst = ws + (size_t)t * 8;
    #pragma unroll
    for (int j = 0; j < 8; ++j)
        dst[j] = f32_to_bf16_rne(W[(kb + j) * DD + n]);
    (void)nt;
}

// One block per batch; 4 waves. Wave w owns n-tiles {2w, 2w+1} x all 4 m-tiles.
__global__ __launch_bounds__(256, 6) void sess_attn(
    const int*   __restrict__ seq_idx,   // [B,L]
    const int*   __restrict__ mask,      // [B,L]
    const float* __restrict__ nodes,     // [B,N,D]
    const float* __restrict__ b_seq,     // [D]
    const float* __restrict__ W_alpha,   // [D]
    const unsigned short* __restrict__ wfrag,  // d_ws, combined B-frags
    float*       __restrict__ out)       // [B*D] v_n, then [B*D] session_graph
{
    const int b    = blockIdx.x;
    const int tid  = threadIdx.x;
    const int lane = tid & 63;
    const int wave = tid >> 6;
    const int col  = lane & 15;
    const int quad = lane >> 4;

    // rows 50..63 intentionally never written (their alpha rows are unused)
    __shared__ __align__(16) unsigned short s_nbf[64][136];  // 17408 B
    __shared__ float s_alpha[64];
    __shared__ float s_cntf[NN];
    __shared__ float s_b[DD];
    __shared__ float s_wa[DD];
    __shared__ int   s_last;

    if (tid < 64) s_alpha[tid] = 0.f;
    if (tid < NN) s_cntf[tid] = 0.f;
    if (tid < DD) { s_b[tid] = b_seq[tid]; s_wa[tid] = W_alpha[tid]; }

    // Stage nodes[b] (50x128 fp32) -> bf16 LDS tile, converting in registers.
    const float* nb = nodes + (size_t)b * (NN * DD);
    for (int i = tid; i < NN * DD / 4; i += 256) {
        float4 v = ((const float4*)nb)[i];
        int r = i >> 5;            // 32 float4 per row
        int c = (i & 31) * 4;
        ushort4 h;
        h.x = f32_to_bf16_rne(v.x);
        h.y = f32_to_bf16_rne(v.y);
        h.z = f32_to_bf16_rne(v.z);
        h.w = f32_to_bf16_rne(v.w);
        *(ushort4*)&s_nbf[r][c] = h;
    }

    // Wave 0: seq_len + last index + histogram of masked indices.
    if (tid < 64) {
        int m = (tid < LL) ? mask[b * LL + tid] : 0;
        int mm = m;
        for (int off = 32; off; off >>= 1) mm += __shfl_down(mm, off);
        if (tid == 0) {
            int j = mm - 1;
            if (j < 0) j += LL;            // JAX negative-index wrap
            s_last = seq_idx[b * LL + j];
        }
        if (tid < LL && m) atomicAdd(&s_cntf[seq_idx[b * LL + tid]], (float)m);
    }
    __syncthreads();   // s_nbf, s_last, s_cntf, s_b, s_wa, s_alpha ready

    const int last = s_last;

    // v_n output: exact fp32, re-read from global (L2-hot after staging).
    if (tid < DD) out[(size_t)b * DD + tid] = nb[last * DD + tid];

    // MFMA over extended K=256: kk<4 uses node rows vs W_seq frags,
    // kk>=4 uses broadcast v_n row vs W_last frags.
    f32x4 acc[4][2];
    #pragma unroll
    for (int m = 0; m < 4; ++m)
        #pragma unroll
        for (int j = 0; j < 2; ++j)
            acc[m][j] = (f32x4){0.f, 0.f, 0.f, 0.f};

    const bf16x8* wsf = (const bf16x8*)wfrag;
    #pragma unroll
    for (int kk = 0; kk < 8; ++kk) {
        bf16x8 a[4];
        if (kk < 4) {
            #pragma unroll
            for (int m = 0; m < 4; ++m)
                a[m] = *(const bf16x8*)&s_nbf[m * 16 + col][kk * 32 + quad * 8];
        } else {
            bf16x8 av = *(const bf16x8*)&s_nbf[last][(kk - 4) * 32 + quad * 8];
            a[0] = av; a[1] = av; a[2] = av; a[3] = av;
        }
        #pragma unroll
        for (int j = 0; j < 2; ++j) {
            bf16x8 bf = wsf[(size_t)((kk * 8 + (wave * 2 + j)) * 64 + lane)];
            #pragma unroll
            for (int m = 0; m < 4; ++m)
                acc[m][j] = __builtin_amdgcn_mfma_f32_16x16x32_bf16(a[m], bf, acc[m][j], 0, 0, 0);
        }
    }

    // Epilogue: alpha[row] += sum over this wave's 32 cols of sigmoid(x)*W_alpha.
    // C layout: col = lane&15, row = m*16 + quad*4 + r.
    #pragma unroll
    for (int m = 0; m < 4; ++m) {
        float p[4] = {0.f, 0.f, 0.f, 0.f};
        #pragma unroll
        for (int j = 0; j < 2; ++j) {
            int n = (wave * 2 + j) * 16 + col;
            float bb = s_b[n];
            float wa = s_wa[n];
            #pragma unroll
            for (int r = 0; r < 4; ++r) {
                float x = acc[m][j][r] + bb;
                float sig = 1.f / (1.f + __expf(-x));
                p[r] = fmaf(sig, wa, p[r]);
            }
        }
        #pragma unroll
        for (int r = 0; r < 4; ++r) {
            float v = p[r];
            v += __shfl_xor(v, 1);
            v += __shfl_xor(v, 2);
            v += __shfl_xor(v, 4);
            v += __shfl_xor(v, 8);
            int row = m * 16 + quad * 4 + r;
            if (col == 0 && row < NN) atomicAdd(&s_alpha[row], v);
        }
    }
    __syncthreads();   // s_alpha complete

    // session_graph[d] = sum_n cnt[n]*alpha[n]*nodes_bf16[n][d]
    if (tid < DD) {
        float acc2 = 0.f;
        #pragma unroll 10
        for (int n = 0; n < NN; ++n)
            acc2 = fmaf(s_cntf[n] * s_alpha[n], bf16_to_f32(s_nbf[n][tid]), acc2);
        out[(size_t)BB * DD + (size_t)b * DD + tid] = acc2;
    }
}

extern "C" void kernel_launch(void* const* d_in, const int* in_sizes, int n_in,
                              void* d_out, int out_size, void* d_ws, size_t ws_size,
                              hipStream_t stream) {
    const int*   seq     = (const int*)  d_in[0];
    const int*   mask    = (const int*)  d_in[1];
    const float* nodes   = (const float*)d_in[2];
    // d_in[3] = batch_size scalar (shapes compile-time fixed)
    const float* W_last  = (const float*)d_in[4];
    const float* W_seq   = (const float*)d_in[5];
    const float* b_seq   = (const float*)d_in[6];
    const float* W_alpha = (const float*)d_in[7];
    float*       out     = (float*)      d_out;

    unsigned short* wsf = (unsigned short*)d_ws;   // 64 KB combined B-fragments

    prep_w<<<16, 256, 0, stream>>>(W_seq, W_last, wsf);
    sess_attn<<<BB, 256, 0, stream>>>(seq, mask, nodes, b_seq, W_alpha, wsf, out);
}